// Round 6
// baseline (65.714 us; speedup 1.0000x reference)
//
#include <hip/hip_runtime.h>

#define NC 20
#define THREADS 256
#define BLOCKS 2048
#define GRAN 8             // int4 granules/thread: 2048*256*8 = 4,194,304 = n/4 exactly
#define EPSF 1e-10f
#define CPAD 8             // u64 stride per counter -> each on its own 64B line

typedef unsigned long long u64;
typedef unsigned int u32;

// One-hot (3-bit fields, 20 classes in 60 bits) accumulate for one pair.
static __device__ __forceinline__ void pair_update(int p, int t,
                                                   u64& np, u64& nt, u64& ne)
{
    u64 ip = 1ull << (3 * p);
    u64 it = 1ull << (3 * t);
    np += ip;
    nt += it;
    ne += (p == t) ? ip : 0ull;   // branchless
}

// Bit-sliced joint counting, depth-2 software-pipelined loads, no LDS in the
// hot loop, shuffle-reduce epilogue, line-padded global atomics.
__global__ __launch_bounds__(THREADS, 4) void dice_slice(
    const int* __restrict__ pred, const int* __restrict__ tgt,
    u64* __restrict__ gc)
{
    constexpr u64 M = 0x01C71C71C71C71C7ull;  // 6-bit-spaced 3-bit mask (10 slots)
    __shared__ u32 swave[4][30];
    const int tid = threadIdx.x;
    const int g   = blockIdx.x * THREADS + tid;
    const int S   = BLOCKS * THREADS;
    const int4* p4 = (const int4*)pred;
    const int4* t4 = (const int4*)tgt;

    // 6-bit-spaced accumulators, even classes in *e*, odd in *o*.
    // Per-class per-thread max = GRAN*4 = 32 <= 63: single bank is safe.
    u64 aeP=0, aoP=0, aeT=0, aoT=0, aeE=0, aoE=0;

    // Depth-2 pipeline: granules k+1, k+2 always in flight while counting k.
    int4 P0 = p4[g],     T0 = t4[g];
    int4 P1 = p4[g + S], T1 = t4[g + S];
    #pragma unroll
    for (int k = 0; k < GRAN; ++k) {
        int4 Pn = P1, Tn = T1;
        if (k + 2 < GRAN) { Pn = p4[g + (k + 2) * S]; Tn = t4[g + (k + 2) * S]; }
        u64 np = 0, nt = 0, ne = 0;              // in-granule 3-bit fields (max 4 <= 7)
        pair_update(P0.x, T0.x, np, nt, ne);
        pair_update(P0.y, T0.y, np, nt, ne);
        pair_update(P0.z, T0.z, np, nt, ne);
        pair_update(P0.w, T0.w, np, nt, ne);
        aeP += np & M;        aoP += (np >> 3) & M;
        aeT += nt & M;        aoT += (nt >> 3) & M;
        aeE += ne & M;        aoE += (ne >> 3) & M;
        P0 = P1; T0 = T1; P1 = Pn; T1 = Tn;
    }

    // Widen to u16-packed (class 2j | class 2j+1 << 16) and wave-reduce.
    // Wave sums per class <= 64*32 = 2048 per half: no cross-carry.
    const int wid  = tid >> 6;
    const int lane = tid & 63;
    #pragma unroll
    for (int j = 0; j < 10; ++j) {
        const int sh = 6 * j;
        u32 sP = (u32)((aeP >> sh) & 63) | ((u32)((aoP >> sh) & 63) << 16);
        u32 sT = (u32)((aeT >> sh) & 63) | ((u32)((aoT >> sh) & 63) << 16);
        u32 sE = (u32)((aeE >> sh) & 63) | ((u32)((aoE >> sh) & 63) << 16);
        #pragma unroll
        for (int d = 32; d >= 1; d >>= 1) {
            sP += __shfl_down(sP, d, 64);
            sT += __shfl_down(sT, d, 64);
            sE += __shfl_down(sE, d, 64);
        }
        if (lane == 0) {
            swave[wid][j]      = sP;
            swave[wid][10 + j] = sT;
            swave[wid][20 + j] = sE;
        }
    }
    __syncthreads();

    // Block sums per half <= 4*2048 = 8192: u16 halves still safe.
    // One u64 atomic per packed counter, each on its own cache line.
    if (tid < 30) {
        u32 s = swave[0][tid] + swave[1][tid] + swave[2][tid] + swave[3][tid];
        u64 v = (u64)(s & 0xFFFFu) | ((u64)(s >> 16) << 32);
        atomicAdd(&gc[tid * CPAD], v);
    }
}

// Generic fallback (any n divisible by 4): joint-histogram kernel.
__global__ __launch_bounds__(THREADS) void dice_joint(
    const int* __restrict__ pred, const int* __restrict__ tgt,
    u64* __restrict__ gc, long long n4)
{
    __shared__ u32 h[4 * NC * NC];
    const int tid = threadIdx.x;
    for (int k = tid; k < 4 * NC * NC; k += THREADS) h[k] = 0u;
    __syncthreads();
    u32* hw = &h[(tid >> 6) * NC * NC];
    const int4* p4 = (const int4*)pred;
    const int4* t4 = (const int4*)tgt;
    const long long stride = (long long)2048 * THREADS;
    for (long long i = (long long)blockIdx.x * THREADS + tid; i < n4; i += stride) {
        int4 P = p4[i];
        int4 T = t4[i];
        atomicAdd(&hw[P.x * NC + T.x], 1u);
        atomicAdd(&hw[P.y * NC + T.y], 1u);
        atomicAdd(&hw[P.z * NC + T.z], 1u);
        atomicAdd(&hw[P.w * NC + T.w], 1u);
    }
    __syncthreads();
    for (int k = tid; k < NC * NC; k += THREADS)
        h[k] = h[k] + h[NC*NC + k] + h[2*NC*NC + k] + h[3*NC*NC + k];
    __syncthreads();
    if (tid < 3 * (NC - 1)) {
        const int which = tid / (NC - 1);
        const int c     = tid % (NC - 1) + 1;
        u32 s = 0;
        if (which == 0)      { for (int t = 0; t < NC; ++t) s += h[c * NC + t]; }
        else if (which == 1) { for (int p = 0; p < NC; ++p) s += h[p * NC + c]; }
        else                 { s = h[c * NC + c]; }
        atomicAdd(&gc[(which * 10 + (c >> 1)) * CPAD], (u64)s << (32 * (c & 1)));
    }
}

__global__ void dice_final(const u64* __restrict__ gc, float* __restrict__ out)
{
    const int c = threadIdx.x;  // 64 lanes, classes 1..19 contribute
    float contrib = 0.0f;
    if (c >= 1 && c < NC) {
        const int j = c >> 1, half = c & 1;
        u32 pc = (u32)(gc[(0 * 10 + j) * CPAD] >> (32 * half));
        u32 tc = (u32)(gc[(1 * 10 + j) * CPAD] >> (32 * half));
        u32 tp = (u32)(gc[(2 * 10 + j) * CPAD] >> (32 * half));
        contrib = 2.0f * (float)tp / ((float)pc + (float)tc + EPSF);
    }
    #pragma unroll
    for (int d = 32; d >= 1; d >>= 1) contrib += __shfl_down(contrib, d, 64);
    if (c == 0) out[0] = contrib * (1.0f / 19.0f);
}

extern "C" void kernel_launch(void* const* d_in, const int* in_sizes, int n_in,
                              void* d_out, int out_size, void* d_ws, size_t ws_size,
                              hipStream_t stream) {
    const int* pred = (const int*)d_in[0];
    const int* tgt  = (const int*)d_in[1];
    u64* gc = (u64*)d_ws;

    // d_ws is NOT re-poisoned between replays -> zero the counters each call.
    hipMemsetAsync(d_ws, 0, 30 * CPAD * sizeof(u64), stream);

    const int n  = in_sizes[0];        // 16,777,216
    const int n4 = n >> 2;             // 4,194,304 == BLOCKS*THREADS*GRAN

    if (n4 == BLOCKS * THREADS * GRAN) {
        dice_slice<<<BLOCKS, THREADS, 0, stream>>>(pred, tgt, gc);
    } else {
        dice_joint<<<2048, THREADS, 0, stream>>>(pred, tgt, gc, (long long)n4);
    }
    dice_final<<<1, 64, 0, stream>>>(gc, (float*)d_out);
}